// Round 1
// baseline (144.469 us; speedup 1.0000x reference)
//
#include <hip/hip_runtime.h>
#include <math.h>

#define C_CH 256
#define T_LEN 4096

// ---------------------------------------------------------------------------
// K1: folded drive computation + LIF scan + first-crossing latency + act
// One block per (b, c). 256 threads, each owns a contiguous 16-step chunk.
// ---------------------------------------------------------------------------
__global__ __launch_bounds__(256) void drive_scan_kernel(
    const float* __restrict__ x,
    const float* __restrict__ w3, const float* __restrict__ b3,
    const float* __restrict__ w5, const float* __restrict__ b5,
    const float* __restrict__ w9, const float* __restrict__ b9,
    const float* __restrict__ w_red, const float* __restrict__ b_red,
    const float* __restrict__ latency_scale,
    float* __restrict__ out_lat, float* __restrict__ out_act)
{
    const int blk  = blockIdx.x;       // b*256 + c
    const int b    = blk >> 8;
    const int c    = blk & 255;
    const int tid  = threadIdx.x;
    const int lane = tid & 63;
    const int wv   = tid >> 6;

    __shared__ float sW[3][9];      // folded 9-tap centered kernels
    __shared__ int   sSrc[3];       // source channel per bundle
    __shared__ float sB[3];         // folded path-bias per bundle
    __shared__ float sWaveTot[4];
    __shared__ float sCarry[4];
    __shared__ int   sMin[4];

    // --- fold weights (redundantly per block; 162 MACs, LLC-cached reads) ---
    if (tid < 27) sW[tid / 9][tid % 9] = 0.0f;
    __syncthreads();
    if (tid < 3) {
        const int r  = tid;
        const int q0 = 18 * c + 6 * r;           // bundle start in cat-channel space
        const float* wp; const float* bp; int K; int p0;
        if (q0 < 1536)      { wp = w3; bp = b3; K = 3; p0 = q0; }
        else if (q0 < 3072) { wp = w5; bp = b5; K = 5; p0 = q0 - 1536; }
        else                { wp = w9; bp = b9; K = 9; p0 = q0 - 3072; }
        const int off = (9 - K) >> 1;            // center K-tap kernel in 9 slots
        sSrc[r] = p0 / 6;
        float bacc = 0.0f;
        for (int j = 0; j < 6; ++j) {
            const float wr = w_red[c * 18 + 6 * r + j];
            bacc += wr * bp[p0 + j];
            for (int k = 0; k < K; ++k)
                sW[r][off + k] += wr * wp[(p0 + j) * K + k];
        }
        sB[r] = bacc;
    }
    __syncthreads();

    const float A   = (float)0.8187307530779818;          // exp(-1/5), fp32
    const float OMA = (float)(1.0 - 0.8187307530779818);  // matches ref rounding

    const float Beff = b_red[c] + sB[0] + sB[1] + sB[2];

    // --- compute this thread's 16 drive values ---
    float d[16];
    #pragma unroll
    for (int tt = 0; tt < 16; ++tt) d[tt] = Beff;

    const int i    = tid;
    const int base = 16 * i - 4;                 // window [t-4, t+4], t in [16i,16i+16)
    for (int r = 0; r < 3; ++r) {
        const float* xr = x + ((size_t)b * C_CH + sSrc[r]) * T_LEN;
        float xa[24];
        if (i > 0 && i < 255) {
            const float4* p = (const float4*)(xr + base);  // base % 4 == 0 -> aligned
            #pragma unroll
            for (int v = 0; v < 6; ++v) {
                float4 q = p[v];
                xa[4 * v + 0] = q.x; xa[4 * v + 1] = q.y;
                xa[4 * v + 2] = q.z; xa[4 * v + 3] = q.w;
            }
        } else {
            #pragma unroll
            for (int e = 0; e < 24; ++e) {
                const int t = base + e;
                xa[e] = (t >= 0 && t < T_LEN) ? xr[t] : 0.0f;  // conv zero-pad
            }
        }
        float wk[9];
        #pragma unroll
        for (int k = 0; k < 9; ++k) wk[k] = sW[r][k];
        #pragma unroll
        for (int tt = 0; tt < 16; ++tt) {
            #pragma unroll
            for (int k = 0; k < 9; ++k)
                d[tt] = fmaf(wk[k], xa[tt + k], d[tt]);
        }
    }

    // --- chunk-local scan contribution: V after 16 steps starting from 0 ---
    float S = 0.0f;
    #pragma unroll
    for (int tt = 0; tt < 16; ++tt) S = A * S + OMA * d[tt];

    // --- wave-level weighted inclusive scan, per-chunk decay F = A^16 ---
    const float Fp[6] = {
        (float)4.0762203978366215e-02,  // A^16  = e^-3.2
        (float)1.6615572731739337e-03,  // A^32
        (float)2.7607725720371943e-06,  // A^64
        (float)7.6218649302532563e-12,  // A^128
        (float)5.8092835977683129e-23,  // A^256
        (float)3.3744728758705166e-45   // A^512 (denormal)
    };
    float cinc = S;
    #pragma unroll
    for (int s = 0; s < 6; ++s) {
        const int o = 1 << s;
        const float y = __shfl_up(cinc, o, 64);
        if (lane >= o) cinc = fmaf(Fp[s], y, cinc);
    }
    if (lane == 63) sWaveTot[wv] = cinc;
    __syncthreads();
    if (tid == 0) {
        // A^1024 underflows fp32 -> cross-wave decay factor is exactly 0
        float g = 0.0f;
        for (int w = 0; w < 4; ++w) { sCarry[w] = g; g = sWaveTot[w]; }
    }
    __syncthreads();
    const float cprev = __shfl_up(cinc, 1, 64);
    const float Vin = (lane ? cprev : 0.0f)
                    + expf(-3.2f * (float)lane) * sCarry[wv];

    // --- replay chunk with true incoming V; find first threshold crossing ---
    float V = Vin;
    int firstT = T_LEN;
    #pragma unroll
    for (int tt = 0; tt < 16; ++tt) {
        V = A * V + OMA * d[tt];
        if (V >= 1.0f && firstT == T_LEN) firstT = 16 * i + tt;
    }

    // --- block min-reduce of first crossing ---
    #pragma unroll
    for (int o = 32; o > 0; o >>= 1)
        firstT = min(firstT, __shfl_xor(firstT, o, 64));
    if (lane == 0) sMin[wv] = firstT;
    __syncthreads();
    if (tid == 0) {
        const int f = min(min(sMin[0], sMin[1]), min(sMin[2], sMin[3]));
        const float lat   = (float)f;                          // T if never fired
        const float scale = fmaxf(latency_scale[0], 0.001f);
        out_lat[blk] = lat;
        out_act[blk] = expf(-lat / scale);                     // underflows to 0 at lat=4096
    }
}

// ---------------------------------------------------------------------------
// K2: gated mix + 2-layer MLP + softplus/clip. One block per batch row.
// ---------------------------------------------------------------------------
__global__ __launch_bounds__(256) void mlp_kernel(
    const float* __restrict__ act,
    const float* __restrict__ og, const float* __restrict__ bias,
    const float* __restrict__ W1, const float* __restrict__ b1,
    const float* __restrict__ W2, const float* __restrict__ b2,
    float* __restrict__ out_pred)
{
    const int b = blockIdx.x;
    const int j = threadIdx.x;
    __shared__ float sAct[256];
    __shared__ float sMix[256];
    __shared__ float sH[128];

    sAct[j] = act[b * 256 + j];
    __syncthreads();

    // mixed[b,j] = bias[j] + sum_i act[b,i] * og[j,i]
    float acc = bias[j];
    const float* ogr = og + (size_t)j * 256;
    for (int i2 = 0; i2 < 256; ++i2) acc = fmaf(sAct[i2], ogr[i2], acc);
    sMix[j] = acc;
    __syncthreads();

    // h[k] = relu(b1[k] + sum_j mixed[j] * W1[j,k]) ; W1 is (256,128) row-major
    if (j < 128) {
        float h = b1[j];
        for (int i2 = 0; i2 < 256; ++i2) h = fmaf(sMix[i2], W1[i2 * 128 + j], h);
        sH[j] = fmaxf(h, 0.0f);
    }
    __syncthreads();

    // raw[j] = b2[j] + sum_k h[k] * W2[k,j] ; W2 is (128,256) row-major
    float raw = b2[j];
    for (int k = 0; k < 128; ++k) raw = fmaf(sH[k], W2[k * 256 + j], raw);

    // softplus = logaddexp(x, 0), then clip [0, 4096]
    const float sp = fmaxf(raw, 0.0f) + log1pf(expf(-fabsf(raw)));
    out_pred[b * 256 + j] = fminf(fmaxf(sp, 0.0f), 4096.0f);
}

// ---------------------------------------------------------------------------
extern "C" void kernel_launch(void* const* d_in, const int* in_sizes, int n_in,
                              void* d_out, int out_size, void* d_ws, size_t ws_size,
                              hipStream_t stream) {
    const float* x    = (const float*)d_in[0];
    const float* w3   = (const float*)d_in[1];
    const float* b3   = (const float*)d_in[2];
    const float* w5   = (const float*)d_in[3];
    const float* b5   = (const float*)d_in[4];
    const float* w9   = (const float*)d_in[5];
    const float* b9   = (const float*)d_in[6];
    const float* wred = (const float*)d_in[7];
    const float* bred = (const float*)d_in[8];
    const float* ls   = (const float*)d_in[9];
    const float* og   = (const float*)d_in[10];
    const float* bias = (const float*)d_in[11];
    const float* W1   = (const float*)d_in[12];
    const float* b1   = (const float*)d_in[13];
    const float* W2   = (const float*)d_in[14];
    const float* b2   = (const float*)d_in[15];

    float* out      = (float*)d_out;
    float* out_pred = out;          // (8,256)
    float* out_lat  = out + 2048;   // (8,256)
    float* out_act  = out + 4096;   // (8,256)

    drive_scan_kernel<<<2048, 256, 0, stream>>>(
        x, w3, b3, w5, b5, w9, b9, wred, bred, ls, out_lat, out_act);
    mlp_kernel<<<8, 256, 0, stream>>>(
        out_act, og, bias, W1, b1, W2, b2, out_pred);
}

// Round 2
// 139.998 us; speedup vs baseline: 1.0319x; 1.0319x over previous
//
#include <hip/hip_runtime.h>
#include <math.h>

#define C_CH 256
#define T_LEN 4096

// d_ws layout: per channel c, 32 words:
//   [0..26]  folded weights w[r][k] (r*9+k)
//   [27]     Beff (b_red[c] + sum of folded path biases)
//   [28..30] src channel per bundle (int bitcast)
//   [31]     pad
// total 256*32*4 = 32 KB

// ---------------------------------------------------------------------------
// K0: fold conv weights once. 1 block, 256 threads (one per channel).
// Compile-time K so everything unrolls -> all loads issue concurrently.
// ---------------------------------------------------------------------------
template <int K>
__device__ inline void fold_bundle(const float* __restrict__ wp,
                                   const float* __restrict__ bp,
                                   const float* __restrict__ wred6,
                                   int p0, float* __restrict__ w9,
                                   float& bacc, int& src)
{
    const int off = (9 - K) >> 1;
    src = p0 / 6;
    #pragma unroll
    for (int k = 0; k < 9; ++k) w9[k] = 0.0f;
    #pragma unroll
    for (int j = 0; j < 6; ++j) {
        const float wr = wred6[j];
        bacc += wr * bp[p0 + j];
        #pragma unroll
        for (int k = 0; k < K; ++k)
            w9[off + k] += wr * wp[(p0 + j) * K + k];
    }
}

__global__ __launch_bounds__(256) void fold_kernel(
    const float* __restrict__ w3, const float* __restrict__ b3,
    const float* __restrict__ w5, const float* __restrict__ b5,
    const float* __restrict__ w9, const float* __restrict__ b9,
    const float* __restrict__ w_red, const float* __restrict__ b_red,
    float* __restrict__ ws)
{
    const int c = threadIdx.x;
    float wf[3][9];
    int   src[3];
    float bacc = 0.0f;
    #pragma unroll
    for (int r = 0; r < 3; ++r) {
        const int q0 = 18 * c + 6 * r;
        const float* wred6 = w_red + c * 18 + 6 * r;
        if (q0 < 1536)      fold_bundle<3>(w3, b3, wred6, q0,        wf[r], bacc, src[r]);
        else if (q0 < 3072) fold_bundle<5>(w5, b5, wred6, q0 - 1536, wf[r], bacc, src[r]);
        else                fold_bundle<9>(w9, b9, wred6, q0 - 3072, wf[r], bacc, src[r]);
    }
    float* o = ws + c * 32;
    #pragma unroll
    for (int r = 0; r < 3; ++r)
        #pragma unroll
        for (int k = 0; k < 9; ++k) o[r * 9 + k] = wf[r][k];
    o[27] = b_red[c] + bacc;
    #pragma unroll
    for (int r = 0; r < 3; ++r) ((int*)o)[28 + r] = src[r];
    o[31] = 0.0f;
}

// ---------------------------------------------------------------------------
// K1: folded drive + LIF scan + first-crossing latency + act.
// One block per (b, c); 256 threads x 16 t-steps each.
// ---------------------------------------------------------------------------
__global__ __launch_bounds__(256) void drive_scan_kernel(
    const float* __restrict__ x,
    const float* __restrict__ ws,
    const float* __restrict__ latency_scale,
    float* __restrict__ out_lat, float* __restrict__ out_act)
{
    const int blk  = blockIdx.x;       // b*256 + c
    const int b    = blk >> 8;
    const int c    = blk & 255;
    const int tid  = threadIdx.x;
    const int lane = tid & 63;
    const int wv   = tid >> 6;

    __shared__ float sWS[32];          // folded weights/bias/src for this c
    __shared__ float sWaveTot[4];
    __shared__ float sCarry[4];
    __shared__ int   sMin[4];

    if (tid < 32) sWS[tid] = ws[c * 32 + tid];
    __syncthreads();

    const float A   = (float)0.8187307530779818;          // exp(-1/5), fp32
    const float OMA = (float)(1.0 - 0.8187307530779818);  // matches ref rounding
    const float Beff = sWS[27];

    // --- this thread's 16 drive values ---
    float d[16];
    #pragma unroll
    for (int tt = 0; tt < 16; ++tt) d[tt] = Beff;

    const int i    = tid;
    const int base = 16 * i - 4;                 // window [t-4, t+4], t in [16i, 16i+16)
    #pragma unroll
    for (int r = 0; r < 3; ++r) {
        const int srcc = ((const int*)sWS)[28 + r];
        const float* xr = x + ((size_t)b * C_CH + srcc) * T_LEN;
        float xa[24];
        if (i > 0 && i < 255) {
            const float4* p = (const float4*)(xr + base);  // base % 4 == 0 -> aligned
            #pragma unroll
            for (int v = 0; v < 6; ++v) {
                float4 q = p[v];
                xa[4 * v + 0] = q.x; xa[4 * v + 1] = q.y;
                xa[4 * v + 2] = q.z; xa[4 * v + 3] = q.w;
            }
        } else {
            #pragma unroll
            for (int e = 0; e < 24; ++e) {
                const int t = base + e;
                xa[e] = (t >= 0 && t < T_LEN) ? xr[t] : 0.0f;  // conv zero-pad
            }
        }
        float wk[9];
        #pragma unroll
        for (int k = 0; k < 9; ++k) wk[k] = sWS[r * 9 + k];
        #pragma unroll
        for (int tt = 0; tt < 16; ++tt) {
            #pragma unroll
            for (int k = 0; k < 9; ++k)
                d[tt] = fmaf(wk[k], xa[tt + k], d[tt]);
        }
    }

    // --- chunk-local scan: V after 16 steps from 0 ---
    float S = 0.0f;
    #pragma unroll
    for (int tt = 0; tt < 16; ++tt) S = A * S + OMA * d[tt];

    // --- wave-level weighted inclusive scan (per-chunk decay A^16) ---
    const float Fp[6] = {
        (float)4.0762203978366215e-02,  // A^16  = e^-3.2
        (float)1.6615572731739337e-03,  // A^32
        (float)2.7607725720371943e-06,  // A^64
        (float)7.6218649302532563e-12,  // A^128
        (float)5.8092835977683129e-23,  // A^256
        (float)3.3744728758705166e-45   // A^512 (denormal)
    };
    float cinc = S;
    #pragma unroll
    for (int s = 0; s < 6; ++s) {
        const int o = 1 << s;
        const float y = __shfl_up(cinc, o, 64);
        if (lane >= o) cinc = fmaf(Fp[s], y, cinc);
    }
    if (lane == 63) sWaveTot[wv] = cinc;
    __syncthreads();
    if (tid == 0) {
        // A^1024 underflows fp32 -> cross-wave decay factor is exactly 0
        float g = 0.0f;
        #pragma unroll
        for (int w = 0; w < 4; ++w) { sCarry[w] = g; g = sWaveTot[w]; }
    }
    __syncthreads();
    const float cprev = __shfl_up(cinc, 1, 64);
    const float Vin = (lane ? cprev : 0.0f)
                    + expf(-3.2f * (float)lane) * sCarry[wv];

    // --- replay chunk with true incoming V; first threshold crossing ---
    float V = Vin;
    int firstT = T_LEN;
    #pragma unroll
    for (int tt = 0; tt < 16; ++tt) {
        V = A * V + OMA * d[tt];
        if (V >= 1.0f && firstT == T_LEN) firstT = 16 * i + tt;
    }

    // --- block min-reduce ---
    #pragma unroll
    for (int o = 32; o > 0; o >>= 1)
        firstT = min(firstT, __shfl_xor(firstT, o, 64));
    if (lane == 0) sMin[wv] = firstT;
    __syncthreads();
    if (tid == 0) {
        const int f = min(min(sMin[0], sMin[1]), min(sMin[2], sMin[3]));
        const float lat   = (float)f;                          // T if never fired
        const float scale = fmaxf(latency_scale[0], 0.001f);
        out_lat[blk] = lat;
        out_act[blk] = expf(-lat / scale);
    }
}

// ---------------------------------------------------------------------------
// K2: gated mix + 2-layer MLP + softplus/clip. One block per batch row.
// ---------------------------------------------------------------------------
__global__ __launch_bounds__(256) void mlp_kernel(
    const float* __restrict__ act,
    const float* __restrict__ og, const float* __restrict__ bias,
    const float* __restrict__ W1, const float* __restrict__ b1,
    const float* __restrict__ W2, const float* __restrict__ b2,
    float* __restrict__ out_pred)
{
    const int b = blockIdx.x;
    const int j = threadIdx.x;
    __shared__ float sAct[256];
    __shared__ float sMix[256];
    __shared__ float sH[128];

    sAct[j] = act[b * 256 + j];
    __syncthreads();

    float acc = bias[j];
    const float* ogr = og + (size_t)j * 256;
    for (int i2 = 0; i2 < 256; ++i2) acc = fmaf(sAct[i2], ogr[i2], acc);
    sMix[j] = acc;
    __syncthreads();

    if (j < 128) {
        float h = b1[j];
        for (int i2 = 0; i2 < 256; ++i2) h = fmaf(sMix[i2], W1[i2 * 128 + j], h);
        sH[j] = fmaxf(h, 0.0f);
    }
    __syncthreads();

    float raw = b2[j];
    for (int k = 0; k < 128; ++k) raw = fmaf(sH[k], W2[k * 256 + j], raw);

    const float sp = fmaxf(raw, 0.0f) + log1pf(expf(-fabsf(raw)));
    out_pred[b * 256 + j] = fminf(fmaxf(sp, 0.0f), 4096.0f);
}

// ---------------------------------------------------------------------------
extern "C" void kernel_launch(void* const* d_in, const int* in_sizes, int n_in,
                              void* d_out, int out_size, void* d_ws, size_t ws_size,
                              hipStream_t stream) {
    const float* x    = (const float*)d_in[0];
    const float* w3   = (const float*)d_in[1];
    const float* b3   = (const float*)d_in[2];
    const float* w5   = (const float*)d_in[3];
    const float* b5   = (const float*)d_in[4];
    const float* w9   = (const float*)d_in[5];
    const float* b9   = (const float*)d_in[6];
    const float* wred = (const float*)d_in[7];
    const float* bred = (const float*)d_in[8];
    const float* ls   = (const float*)d_in[9];
    const float* og   = (const float*)d_in[10];
    const float* bias = (const float*)d_in[11];
    const float* W1   = (const float*)d_in[12];
    const float* b1   = (const float*)d_in[13];
    const float* W2   = (const float*)d_in[14];
    const float* b2   = (const float*)d_in[15];

    float* ws       = (float*)d_ws;     // 32 KB folded-weight table
    float* out      = (float*)d_out;
    float* out_pred = out;              // (8,256)
    float* out_lat  = out + 2048;       // (8,256)
    float* out_act  = out + 4096;       // (8,256)

    fold_kernel<<<1, 256, 0, stream>>>(w3, b3, w5, b5, w9, b9, wred, bred, ws);
    drive_scan_kernel<<<2048, 256, 0, stream>>>(x, ws, ls, out_lat, out_act);
    mlp_kernel<<<8, 256, 0, stream>>>(out_act, og, bias, W1, b1, W2, b2, out_pred);
}